// Round 4
// baseline (784.876 us; speedup 1.0000x reference)
//
#include <hip/hip_runtime.h>
#include <hip/hip_bf16.h>

#define T_DIM 256
#define B_DIM 128
#define C_DIM 1024
#define H_DIM 1024
#define L_DIM 6
#define NC_DIM 1000
#define M_DIM (T_DIM * B_DIM)    // 32768
#define BH_DIM (B_DIM * H_DIM)   // 131072

typedef __attribute__((ext_vector_type(8))) short bf16x8;
typedef __attribute__((ext_vector_type(4))) float f32x4;

__device__ __forceinline__ float bf2f(unsigned short u) {
  union { unsigned int i; float f; } v; v.i = ((unsigned int)u) << 16; return v.f;
}
__device__ __forceinline__ unsigned short f2bf(float f) {
  union { float f; unsigned int i; } v; v.f = f;
  unsigned int r = v.i + 0x7fffu + ((v.i >> 16) & 1u);  // RNE
  return (unsigned short)(r >> 16);
}

__device__ __forceinline__ void gload_lds16(const void* g, void* l) {
  __builtin_amdgcn_global_load_lds(
      (const __attribute__((address_space(1))) unsigned int*)g,
      (__attribute__((address_space(3))) unsigned int*)l, 16, 0, 0);
}

// ---------------- x f32 -> bf16 convert ----------------
__global__ __launch_bounds__(256) void f32_to_bf16_kernel(
    const float* __restrict__ in, unsigned short* __restrict__ out, int n4) {
  int stride = gridDim.x * blockDim.x;
  for (int i = blockIdx.x * blockDim.x + threadIdx.x; i < n4; i += stride) {
    float4 v = ((const float4*)in)[i];
    ushort4 o;
    o.x = f2bf(v.x); o.y = f2bf(v.y); o.z = f2bf(v.z); o.w = f2bf(v.w);
    ((ushort4*)out)[i] = o;
  }
}

// ---------------- W (L,C,H) f32 -> Wt (L,H,C) bf16 ----------------
__global__ __launch_bounds__(256) void wtrans_kernel(
    const float* __restrict__ W, unsigned short* __restrict__ Wt) {
  __shared__ float tile[32][33];
  int l = blockIdx.z;
  const float* Wl = W + (size_t)l * C_DIM * H_DIM;
  unsigned short* Wtl = Wt + (size_t)l * C_DIM * H_DIM;
  int h0 = blockIdx.x * 32, c0 = blockIdx.y * 32;
  int tx = threadIdx.x, ty = threadIdx.y;  // 32 x 8
#pragma unroll
  for (int i = 0; i < 32; i += 8)
    tile[ty + i][tx] = Wl[(size_t)(c0 + ty + i) * H_DIM + h0 + tx];
  __syncthreads();
#pragma unroll
  for (int i = 0; i < 32; i += 8)
    Wtl[(size_t)(h0 + ty + i) * C_DIM + c0 + tx] = f2bf(tile[tx][ty + i]);
}

// ---------------- GEMM 256x128 tile, BK=32, 2-buffer pipeline, 2 blocks/CU ----------------
// Z(bf16, M x H) = A(bf16, M x K) * Wt(bf16, N x K)^T, fused BN partial stats (f32-exact).
// 8 waves (4M x 2N), per-wave 64x64 output (4x4 16x16 frags) -> ~115 regs => 4 waves/EU.
// LDS: 2 buffers x (A 16KB + B 8KB) = 48 KiB => 2 blocks/CU; cross-block overlap
// covers per-phase ds_read latency + vmcnt drain (T3 minimum-2-phase recipe).
// Swizzle: 16B-chunk ^= (row>>1)&3 => 2-way bank aliasing (free) on ds_read_b128.
#define NT 32  // K / 32

__global__ __launch_bounds__(512, 4) void gemm_kernel(
    const unsigned short* __restrict__ A, const unsigned short* __restrict__ Bt,
    unsigned short* __restrict__ Z, float* __restrict__ psum, float* __restrict__ psqs) {
  extern __shared__ char lds[];
  int bid = blockIdx.x;              // 1024 blocks, %8==0 -> bijective XCD swizzle
  int swz = (bid & 7) * 128 + (bid >> 3);
  int tm = swz >> 3, tn = swz & 7;   // 128 x 8 tiles
  int tid = threadIdx.x;
  int wv = tid >> 6, ln = tid & 63;
  int wm = wv >> 1, wn = wv & 1;     // 4 x 2 wave grid

  // ---- staging precompute (pre-swizzled global source, linear LDS dest) ----
  const char* Asrc = (const char*)A + (size_t)tm * 256 * 2048;   // row stride 2048B
  const char* Bsrc = (const char*)Bt + (size_t)tn * 128 * 2048;
  int p0 = wv * 1024 + ln * 16;          // A phys byte, load 0 (rows 0..127)
  int p1 = 8192 + wv * 1024 + ln * 16;   // A phys byte, load 1 (rows 128..255)
  int pB = wv * 1024 + ln * 16;          // B phys byte (rows 0..127)
  int l0 = p0 ^ (((p0 >> 7) & 3) << 4);  // involution: chunk ^= (row>>1)&3
  int l1 = p1 ^ (((p1 >> 7) & 3) << 4);
  int lB = pB ^ (((pB >> 7) & 3) << 4);
  int ro0 = (p0 >> 6) * 2048 + (l0 & 63);
  int ro1 = (p1 >> 6) * 2048 + (l1 & 63);
  int roB = (pB >> 6) * 2048 + (lB & 63);
  int dst0 = wv * 1024;                  // wave-uniform LDS bases (+ lane*16 by HW)
  int dst1 = 8192 + wv * 1024;
  int dstB = 16384 + wv * 1024;

  // swizzled ds_read lane offset: row s=(ln&15), chunk=(ln>>4)^((s>>1)&3)
  int laneoff = (ln & 15) * 64 + ((((ln >> 4) ^ ((ln & 15) >> 1)) & 3) << 4);

  f32x4 acc[4][4];
  f32x4 zero = {0.f, 0.f, 0.f, 0.f};
#pragma unroll
  for (int m = 0; m < 4; ++m)
#pragma unroll
    for (int n = 0; n < 4; ++n) acc[m][n] = zero;

  auto stage = [&](int t) {
    char* ldsb = lds + ((t & 1) * 24576);
    int ko = t * 64;
    gload_lds16(Asrc + ro0 + ko, ldsb + dst0);
    gload_lds16(Asrc + ro1 + ko, ldsb + dst1);
    gload_lds16(Bsrc + roB + ko, ldsb + dstB);
  };

  auto body = [&](int t, bool dostage) {
    const char* buf = lds + ((t & 1) * 24576);
    if (dostage) stage(t + 1);           // issue next-tile loads first (T3 recipe)
    const char* Ab = buf + wm * 4096;
    const char* Bb = buf + 16384 + wn * 4096;
    bf16x8 a[4], b[4];
#pragma unroll
    for (int m = 0; m < 4; ++m) a[m] = *(const bf16x8*)(Ab + m * 1024 + laneoff);
#pragma unroll
    for (int n = 0; n < 4; ++n) b[n] = *(const bf16x8*)(Bb + n * 1024 + laneoff);
    __builtin_amdgcn_s_setprio(1);
#pragma unroll
    for (int m = 0; m < 4; ++m)
#pragma unroll
      for (int n = 0; n < 4; ++n)
        acc[m][n] = __builtin_amdgcn_mfma_f32_16x16x32_bf16(a[m], b[n], acc[m][n], 0, 0, 0);
    __builtin_amdgcn_s_setprio(0);
  };

  stage(0);
  asm volatile("s_waitcnt vmcnt(0)" ::: "memory");
  __builtin_amdgcn_s_barrier();

  for (int t = 0; t < NT - 1; ++t) {
    body(t, true);
    asm volatile("s_waitcnt vmcnt(0)" ::: "memory");  // next tile landed (issued early)
    __builtin_amdgcn_s_barrier();
  }
  body(NT - 1, false);

  // ---- epilogue: fused BN partial stats (exact f32) + bf16 Z write ----
  // C/D layout: col = ln&15, row = (ln>>4)*4 + reg
  float s[4], q[4];
#pragma unroll
  for (int n = 0; n < 4; ++n) {
    float sv = 0.f, qv = 0.f;
#pragma unroll
    for (int m = 0; m < 4; ++m)
#pragma unroll
      for (int r = 0; r < 4; ++r) {
        float v = acc[m][n][r];
        sv += v; qv += v * v;
      }
    s[n] = sv; q[n] = qv;
  }
#pragma unroll
  for (int n = 0; n < 4; ++n) {
    s[n] += __shfl_xor(s[n], 16); s[n] += __shfl_xor(s[n], 32);
    q[n] += __shfl_xor(q[n], 16); q[n] += __shfl_xor(q[n], 32);
  }
  float* red = (float*)lds;  // buffer 0 region (dead after final phase)
  __syncthreads();
  if (ln < 16) {
#pragma unroll
    for (int n = 0; n < 4; ++n) {
      red[wm * 128 + wn * 64 + n * 16 + ln] = s[n];
      red[512 + wm * 128 + wn * 64 + n * 16 + ln] = q[n];
    }
  }
  __syncthreads();
  if (tid < 128) {
    psum[(size_t)tm * H_DIM + tn * 128 + tid] =
        red[tid] + red[128 + tid] + red[256 + tid] + red[384 + tid];
  } else if (tid < 256) {
    int c = tid - 128;
    psqs[(size_t)tm * H_DIM + tn * 128 + c] =
        red[512 + c] + red[640 + c] + red[768 + c] + red[896 + c];
  }
  // bf16 Z stores
  int r0 = tm * 256 + wm * 64 + ((ln >> 4) << 2);
  int c0 = tn * 128 + wn * 64 + (ln & 15);
#pragma unroll
  for (int m = 0; m < 4; ++m)
#pragma unroll
    for (int n = 0; n < 4; ++n) {
      unsigned short* zp = Z + (size_t)(r0 + m * 16) * H_DIM + c0 + n * 16;
#pragma unroll
      for (int r = 0; r < 4; ++r) zp[(size_t)r * H_DIM] = f2bf(acc[m][n][r]);
    }
}

// ---------------- BN finalize: sum 128 partials per channel ----------------
__global__ __launch_bounds__(256) void bn_finalize_kernel(
    const float* __restrict__ psum, const float* __restrict__ psqs,
    const float* __restrict__ gamma, const float* __restrict__ beta,
    float* __restrict__ ss) {
  int c = blockIdx.x * blockDim.x + threadIdx.x;
  float s = 0.f, q = 0.f;
  for (int i = 0; i < 128; ++i) {
    s += psum[(size_t)i * H_DIM + c];
    q += psqs[(size_t)i * H_DIM + c];
  }
  const float invN = 1.0f / (float)M_DIM;
  float mean = s * invN;
  float var = q * invN - mean * mean;
  float sc = gamma[c] * rsqrtf(var + 1e-5f);
  ss[c] = sc;
  ss[H_DIM + c] = beta[c] - mean * sc;
}

// ---------------- fused BN-apply + IndRNN recurrence (2 ch/thread, bf16 Z) ----------------
__global__ __launch_bounds__(256) void bn_recur_kernel(
    const unsigned short* __restrict__ Z, const float* __restrict__ ss,
    const float* __restrict__ u, unsigned short* __restrict__ Hout) {
  int i2 = blockIdx.x * 256 + threadIdx.x;  // pair index, 0..BH/2-1
  int h0 = (i2 & (H_DIM / 2 - 1)) * 2;
  float sc0 = ss[h0], sc1 = ss[h0 + 1];
  float sh0 = ss[H_DIM + h0], sh1 = ss[H_DIM + h0 + 1];
  float u0 = u[h0], u1 = u[h0 + 1];
  float hv0 = 0.f, hv1 = 0.f;
  const unsigned int* Zp = (const unsigned int*)Z;
#pragma unroll 16
  for (int t = 0; t < T_DIM; ++t) {
    unsigned int zz = Zp[(size_t)t * (BH_DIM / 2) + i2];
    float z0 = fmaf(bf2f((unsigned short)(zz & 0xffffu)), sc0, sh0);
    float z1 = fmaf(bf2f((unsigned short)(zz >> 16)), sc1, sh1);
    hv0 = fmaxf(fmaf(u0, hv0, z0), 0.f);
    hv1 = fmaxf(fmaf(u1, hv1, z1), 0.f);
    ushort2 o; o.x = f2bf(hv0); o.y = f2bf(hv1);
    ((ushort2*)Hout)[(size_t)t * (BH_DIM / 2) + i2] = o;
  }
}

// ---------------- classifier ----------------
__global__ __launch_bounds__(256) void classifier_kernel(
    const unsigned short* __restrict__ hlast, const float* __restrict__ Wc,
    const float* __restrict__ bc, float* __restrict__ out) {
  __shared__ float hs[H_DIM];
  int b = blockIdx.y;
  int n = blockIdx.x * 256 + threadIdx.x;
  for (int k = threadIdx.x; k < H_DIM; k += 256)
    hs[k] = bf2f(hlast[(size_t)b * H_DIM + k]);
  __syncthreads();
  if (n < NC_DIM) {
    float acc = bc[n];
#pragma unroll 8
    for (int k = 0; k < H_DIM; ++k)
      acc = fmaf(hs[k], Wc[(size_t)k * NC_DIM + n], acc);
    out[(size_t)b * NC_DIM + n] = acc;
  }
}

extern "C" void kernel_launch(void* const* d_in, const int* in_sizes, int n_in,
                              void* d_out, int out_size, void* d_ws, size_t ws_size,
                              hipStream_t stream) {
  const float* x     = (const float*)d_in[0];
  const float* W     = (const float*)d_in[1];
  // d_in[2] = b: cancels under BatchNorm (shift-invariant)
  const float* gamma = (const float*)d_in[3];
  const float* beta  = (const float*)d_in[4];
  const float* u     = (const float*)d_in[5];
  const float* Wc    = (const float*)d_in[6];
  const float* bc    = (const float*)d_in[7];
  float* out = (float*)d_out;

  const size_t CH = (size_t)C_DIM * H_DIM;
  const size_t MH = (size_t)M_DIM * H_DIM;
  char* p = (char*)d_ws;
  unsigned short* Wt = (unsigned short*)p; p += L_DIM * CH * sizeof(unsigned short);
  unsigned short* Ha = (unsigned short*)p; p += MH * sizeof(unsigned short);
  unsigned short* Hb = (unsigned short*)p; p += MH * sizeof(unsigned short);
  unsigned short* Z  = (unsigned short*)p; p += MH * sizeof(unsigned short);
  float* psum = (float*)p; p += 128 * H_DIM * sizeof(float);
  float* psqs = (float*)p; p += 128 * H_DIM * sizeof(float);
  float* ss   = (float*)p; p += 2 * H_DIM * sizeof(float);

  f32_to_bf16_kernel<<<2048, 256, 0, stream>>>(x, Ha, (int)(MH / 4));
  wtrans_kernel<<<dim3(H_DIM / 32, C_DIM / 32, L_DIM), dim3(32, 8), 0, stream>>>(W, Wt);

  unsigned short* cur = Ha;
  unsigned short* nxt = Hb;
  for (int l = 0; l < L_DIM; ++l) {
    gemm_kernel<<<(M_DIM / 256) * (H_DIM / 128), 512, 49152, stream>>>(
        cur, Wt + (size_t)l * CH, Z, psum, psqs);
    bn_finalize_kernel<<<4, 256, 0, stream>>>(psum, psqs, gamma + (size_t)l * H_DIM,
                                              beta + (size_t)l * H_DIM, ss);
    bn_recur_kernel<<<BH_DIM / 512, 256, 0, stream>>>(Z, ss, u + (size_t)l * H_DIM, nxt);
    unsigned short* tmp = cur; cur = nxt; nxt = tmp;
  }
  classifier_kernel<<<dim3(4, B_DIM), 256, 0, stream>>>(
      cur + (size_t)(T_DIM - 1) * BH_DIM, Wc, bc, out);
}

// Round 5
// 759.977 us; speedup vs baseline: 1.0328x; 1.0328x over previous
//
#include <hip/hip_runtime.h>
#include <hip/hip_bf16.h>

#define T_DIM 256
#define B_DIM 128
#define C_DIM 1024
#define H_DIM 1024
#define L_DIM 6
#define NC_DIM 1000
#define M_DIM (T_DIM * B_DIM)    // 32768
#define BH_DIM (B_DIM * H_DIM)   // 131072

typedef __attribute__((ext_vector_type(8))) short bf16x8;
typedef __attribute__((ext_vector_type(4))) float f32x4;

__device__ __forceinline__ float bf2f(unsigned short u) {
  union { unsigned int i; float f; } v; v.i = ((unsigned int)u) << 16; return v.f;
}
__device__ __forceinline__ unsigned short f2bf(float f) {
  union { float f; unsigned int i; } v; v.f = f;
  unsigned int r = v.i + 0x7fffu + ((v.i >> 16) & 1u);  // RNE
  return (unsigned short)(r >> 16);
}

__device__ __forceinline__ void gload_lds16(const void* g, void* l) {
  __builtin_amdgcn_global_load_lds(
      (const __attribute__((address_space(1))) unsigned int*)g,
      (__attribute__((address_space(3))) unsigned int*)l, 16, 0, 0);
}

// ---------------- x f32 -> bf16 convert ----------------
__global__ __launch_bounds__(256) void f32_to_bf16_kernel(
    const float* __restrict__ in, unsigned short* __restrict__ out, int n4) {
  int stride = gridDim.x * blockDim.x;
  for (int i = blockIdx.x * blockDim.x + threadIdx.x; i < n4; i += stride) {
    float4 v = ((const float4*)in)[i];
    ushort4 o;
    o.x = f2bf(v.x); o.y = f2bf(v.y); o.z = f2bf(v.z); o.w = f2bf(v.w);
    ((ushort4*)out)[i] = o;
  }
}

// ---------------- W (L,C,H) f32 -> Wt (L,H,C) bf16 ----------------
__global__ __launch_bounds__(256) void wtrans_kernel(
    const float* __restrict__ W, unsigned short* __restrict__ Wt) {
  __shared__ float tile[32][33];
  int l = blockIdx.z;
  const float* Wl = W + (size_t)l * C_DIM * H_DIM;
  unsigned short* Wtl = Wt + (size_t)l * C_DIM * H_DIM;
  int h0 = blockIdx.x * 32, c0 = blockIdx.y * 32;
  int tx = threadIdx.x, ty = threadIdx.y;  // 32 x 8
#pragma unroll
  for (int i = 0; i < 32; i += 8)
    tile[ty + i][tx] = Wl[(size_t)(c0 + ty + i) * H_DIM + h0 + tx];
  __syncthreads();
#pragma unroll
  for (int i = 0; i < 32; i += 8)
    Wtl[(size_t)(h0 + ty + i) * C_DIM + c0 + tx] = f2bf(tile[tx][ty + i]);
}

// ---------------- GEMM 256x256 tile, BK=32, 4-buffer, fine 2-phase interleave ----------------
// Z(bf16, M x H) = A(bf16, M x K) * Wt(bf16, N x K)^T, fused BN partial stats (f32-exact).
// 8 waves (2M x 4N), per-wave 128x64 output (8x4 16x16 frags).
// LDS: 4 buffers x (A 16KB + B 16KB) = 128 KiB; zero-conflict XOR swizzle
//   (16B chunk ^= (row>>1)&3, verified round 3: SQ_LDS_BANK_CONFLICT = 0).
// Counted vmcnt(8) once per K-tile (tiles t+2,t+3 stay in flight).
// NEW: per-tile body split into two template-style phases (m196/m201 recipe):
//   {ds_read B+A_low || stage A(t+3)} -> barrier -> setprio+MFMA -> barrier
//   {ds_read A_high  || stage B(t+3)} -> setprio+MFMA -> vmcnt(8) -> barrier
#define NT 32  // K / 32

__global__ __launch_bounds__(512, 2) void gemm_kernel(
    const unsigned short* __restrict__ A, const unsigned short* __restrict__ Bt,
    unsigned short* __restrict__ Z, float* __restrict__ psum, float* __restrict__ psqs) {
  extern __shared__ char lds[];
  int bid = blockIdx.x;              // 512 blocks, %8==0 -> bijective XCD swizzle
  int swz = (bid & 7) * 64 + (bid >> 3);
  int tm = swz >> 2, tn = swz & 3;   // 128 x 4 tiles
  int tid = threadIdx.x;
  int wv = tid >> 6, ln = tid & 63;
  int wm = wv >> 2, wn = wv & 3;     // 2 x 4 wave grid

  // ---- staging precompute (pre-swizzled global source, linear LDS dest) ----
  const char* Asrc = (const char*)A + (size_t)tm * 256 * 2048;   // row stride 2048B
  const char* Bsrc = (const char*)Bt + (size_t)tn * 256 * 2048;
  int p0 = wv * 1024 + ln * 16;          // physical byte (load 0, rows 0..127)
  int p1 = 8192 + wv * 1024 + ln * 16;   // physical byte (load 1, rows 128..255)
  int l0 = p0 ^ (((p0 >> 7) & 3) << 4);  // involution: chunk ^= (row>>1)&3
  int l1 = p1 ^ (((p1 >> 7) & 3) << 4);
  int ro0 = (p0 >> 6) * 2048 + (l0 & 63);  // panel byte offset sans k-term
  int ro1 = (p1 >> 6) * 2048 + (l1 & 63);
  int dst0 = wv * 1024;         // wave-uniform LDS dest bases (+ lane*16 by HW)
  int dst1 = 8192 + wv * 1024;

  // swizzled ds_read lane offset: row s=(ln&15), chunk=(ln>>4)^((s>>1)&3)
  int laneoff = (ln & 15) * 64 + ((((ln >> 4) ^ ((ln & 15) >> 1)) & 3) << 4);

  f32x4 acc[8][4];
  f32x4 zero = {0.f, 0.f, 0.f, 0.f};
#pragma unroll
  for (int m = 0; m < 8; ++m)
#pragma unroll
    for (int n = 0; n < 4; ++n) acc[m][n] = zero;

  auto stageA = [&](int t) {
    char* ldsb = lds + ((t & 3) * 32768);
    int ko = t * 64;
    gload_lds16(Asrc + ro0 + ko, ldsb + dst0);
    gload_lds16(Asrc + ro1 + ko, ldsb + dst1);
  };
  auto stageB = [&](int t) {
    char* ldsb = lds + ((t & 3) * 32768);
    int ko = t * 64;
    gload_lds16(Bsrc + ro0 + ko, ldsb + 16384 + dst0);
    gload_lds16(Bsrc + ro1 + ko, ldsb + 16384 + dst1);
  };

  auto body = [&](int t, bool dostage) {
    const char* buf = lds + ((t & 3) * 32768);
    const char* Ab = buf + wm * 8192;
    const char* Bb = buf + 16384 + wn * 4096;
    bf16x8 bf[4], a0[4], a1[4];
    // ---- phase 1: B frags + A-low frags, stage A-half of t+3 ----
#pragma unroll
    for (int n = 0; n < 4; ++n) bf[n] = *(const bf16x8*)(Bb + n * 1024 + laneoff);
#pragma unroll
    for (int m = 0; m < 4; ++m) a0[m] = *(const bf16x8*)(Ab + m * 1024 + laneoff);
    if (dostage) stageA(t + 3);
    __builtin_amdgcn_s_barrier();
    __builtin_amdgcn_s_setprio(1);
#pragma unroll
    for (int m = 0; m < 4; ++m)
#pragma unroll
      for (int n = 0; n < 4; ++n)
        acc[m][n] = __builtin_amdgcn_mfma_f32_16x16x32_bf16(a0[m], bf[n], acc[m][n], 0, 0, 0);
    __builtin_amdgcn_s_setprio(0);
    __builtin_amdgcn_s_barrier();
    // ---- phase 2: A-high frags, stage B-half of t+3 ----
#pragma unroll
    for (int m = 0; m < 4; ++m) a1[m] = *(const bf16x8*)(Ab + 4096 + m * 1024 + laneoff);
    if (dostage) stageB(t + 3);
    __builtin_amdgcn_s_setprio(1);
#pragma unroll
    for (int m = 0; m < 4; ++m)
#pragma unroll
      for (int n = 0; n < 4; ++n)
        acc[m + 4][n] = __builtin_amdgcn_mfma_f32_16x16x32_bf16(a1[m], bf[n], acc[m + 4][n], 0, 0, 0);
    __builtin_amdgcn_s_setprio(0);
  };

  // prologue: tiles 0,1,2 in flight (12 loads); wait tile0 (vmcnt 8 = tiles 1,2)
  stageA(0); stageB(0); stageA(1); stageB(1); stageA(2); stageB(2);
  asm volatile("s_waitcnt vmcnt(8)" ::: "memory");
  __builtin_amdgcn_s_barrier();

  for (int t = 0; t < NT - 3; ++t) {   // t = 0..28, stages t+3 <= 31
    body(t, true);
    asm volatile("s_waitcnt vmcnt(8)" ::: "memory");  // tiles t+2,t+3 stay in flight
    __builtin_amdgcn_s_barrier();
  }
  body(NT - 3, false);
  asm volatile("s_waitcnt vmcnt(4)" ::: "memory");
  __builtin_amdgcn_s_barrier();
  body(NT - 2, false);
  asm volatile("s_waitcnt vmcnt(0)" ::: "memory");
  __builtin_amdgcn_s_barrier();
  body(NT - 1, false);

  // ---- epilogue: fused BN partial stats (exact f32) + bf16 Z write ----
  // C/D layout: col = ln&15, row = (ln>>4)*4 + reg
  float s[4], q[4];
#pragma unroll
  for (int n = 0; n < 4; ++n) {
    float sv = 0.f, qv = 0.f;
#pragma unroll
    for (int m = 0; m < 8; ++m)
#pragma unroll
      for (int r = 0; r < 4; ++r) {
        float v = acc[m][n][r];
        sv += v; qv += v * v;
      }
    s[n] = sv; q[n] = qv;
  }
#pragma unroll
  for (int n = 0; n < 4; ++n) {
    s[n] += __shfl_xor(s[n], 16); s[n] += __shfl_xor(s[n], 32);
    q[n] += __shfl_xor(q[n], 16); q[n] += __shfl_xor(q[n], 32);
  }
  float* red = (float*)lds;  // buffer 0 region (dead after final phase)
  if (ln < 16) {
#pragma unroll
    for (int n = 0; n < 4; ++n) {
      red[wm * 256 + wn * 64 + n * 16 + ln] = s[n];
      red[512 + wm * 256 + wn * 64 + n * 16 + ln] = q[n];
    }
  }
  __syncthreads();
  if (tid < 256) {
    psum[(size_t)tm * H_DIM + tn * 256 + tid] = red[tid] + red[256 + tid];
  } else {
    int c = tid - 256;
    psqs[(size_t)tm * H_DIM + tn * 256 + c] = red[512 + c] + red[768 + c];
  }
  // bf16 Z stores
  int r0 = tm * 256 + wm * 128 + ((ln >> 4) << 2);
  int c0 = tn * 256 + wn * 64 + (ln & 15);
#pragma unroll
  for (int m = 0; m < 8; ++m)
#pragma unroll
    for (int n = 0; n < 4; ++n) {
      unsigned short* zp = Z + (size_t)(r0 + m * 16) * H_DIM + c0 + n * 16;
#pragma unroll
      for (int r = 0; r < 4; ++r) zp[(size_t)r * H_DIM] = f2bf(acc[m][n][r]);
    }
}

// ---------------- BN finalize: sum 128 partials per channel ----------------
__global__ __launch_bounds__(256) void bn_finalize_kernel(
    const float* __restrict__ psum, const float* __restrict__ psqs,
    const float* __restrict__ gamma, const float* __restrict__ beta,
    float* __restrict__ ss) {
  int c = blockIdx.x * blockDim.x + threadIdx.x;
  float s = 0.f, q = 0.f;
  for (int i = 0; i < 128; ++i) {
    s += psum[(size_t)i * H_DIM + c];
    q += psqs[(size_t)i * H_DIM + c];
  }
  const float invN = 1.0f / (float)M_DIM;
  float mean = s * invN;
  float var = q * invN - mean * mean;
  float sc = gamma[c] * rsqrtf(var + 1e-5f);
  ss[c] = sc;
  ss[H_DIM + c] = beta[c] - mean * sc;
}

// ---------------- fused BN-apply + IndRNN recurrence (2 ch/thread, bf16 Z) ----------------
// 32-deep static double-buffered prefetch (all indices compile-time): 8 KB/wave
// of loads in flight to cover L3/HBM latency at the grid-limited 1 wave/SIMD.
__global__ __launch_bounds__(256) void bn_recur_kernel(
    const unsigned short* __restrict__ Z, const float* __restrict__ ss,
    const float* __restrict__ u, unsigned short* __restrict__ Hout) {
  int i2 = blockIdx.x * 256 + threadIdx.x;  // pair index, 0..BH/2-1
  int h0 = (i2 & (H_DIM / 2 - 1)) * 2;
  float sc0 = ss[h0], sc1 = ss[h0 + 1];
  float sh0 = ss[H_DIM + h0], sh1 = ss[H_DIM + h0 + 1];
  float u0 = u[h0], u1 = u[h0 + 1];
  float hv0 = 0.f, hv1 = 0.f;
  const size_t ST = BH_DIM / 2;
  const unsigned int* Zt = (const unsigned int*)Z + i2;
  unsigned int* Ht = (unsigned int*)Hout + i2;

  unsigned int za[32], zb[32];
#pragma unroll
  for (int j = 0; j < 32; ++j) za[j] = Zt[(size_t)j * ST];

#pragma unroll
  for (int blk = 0; blk < 4; ++blk) {
    int tA = blk * 64;
    // prefetch B-batch (tA+32 .. tA+63)
#pragma unroll
    for (int j = 0; j < 32; ++j) zb[j] = Zt[(size_t)(tA + 32 + j) * ST];
    // compute A-batch
#pragma unroll
    for (int j = 0; j < 32; ++j) {
      unsigned int zz = za[j];
      float z0 = fmaf(bf2f((unsigned short)(zz & 0xffffu)), sc0, sh0);
      float z1 = fmaf(bf2f((unsigned short)(zz >> 16)), sc1, sh1);
      hv0 = fmaxf(fmaf(u0, hv0, z0), 0.f);
      hv1 = fmaxf(fmaf(u1, hv1, z1), 0.f);
      Ht[(size_t)(tA + j) * ST] = ((unsigned int)f2bf(hv1) << 16) | f2bf(hv0);
    }
    // prefetch next A-batch (tA+64 ..), except on the last block
    if (blk < 3) {
#pragma unroll
      for (int j = 0; j < 32; ++j) za[j] = Zt[(size_t)(tA + 64 + j) * ST];
    }
    // compute B-batch
#pragma unroll
    for (int j = 0; j < 32; ++j) {
      unsigned int zz = zb[j];
      float z0 = fmaf(bf2f((unsigned short)(zz & 0xffffu)), sc0, sh0);
      float z1 = fmaf(bf2f((unsigned short)(zz >> 16)), sc1, sh1);
      hv0 = fmaxf(fmaf(u0, hv0, z0), 0.f);
      hv1 = fmaxf(fmaf(u1, hv1, z1), 0.f);
      Ht[(size_t)(tA + 32 + j) * ST] = ((unsigned int)f2bf(hv1) << 16) | f2bf(hv0);
    }
  }
}

// ---------------- classifier ----------------
__global__ __launch_bounds__(256) void classifier_kernel(
    const unsigned short* __restrict__ hlast, const float* __restrict__ Wc,
    const float* __restrict__ bc, float* __restrict__ out) {
  __shared__ float hs[H_DIM];
  int b = blockIdx.y;
  int n = blockIdx.x * 256 + threadIdx.x;
  for (int k = threadIdx.x; k < H_DIM; k += 256)
    hs[k] = bf2f(hlast[(size_t)b * H_DIM + k]);
  __syncthreads();
  if (n < NC_DIM) {
    float acc = bc[n];
#pragma unroll 8
    for (int k = 0; k < H_DIM; ++k)
      acc = fmaf(hs[k], Wc[(size_t)k * NC_DIM + n], acc);
    out[(size_t)b * NC_DIM + n] = acc;
  }
}

extern "C" void kernel_launch(void* const* d_in, const int* in_sizes, int n_in,
                              void* d_out, int out_size, void* d_ws, size_t ws_size,
                              hipStream_t stream) {
  const float* x     = (const float*)d_in[0];
  const float* W     = (const float*)d_in[1];
  // d_in[2] = b: cancels under BatchNorm (shift-invariant)
  const float* gamma = (const float*)d_in[3];
  const float* beta  = (const float*)d_in[4];
  const float* u     = (const float*)d_in[5];
  const float* Wc    = (const float*)d_in[6];
  const float* bc    = (const float*)d_in[7];
  float* out = (float*)d_out;

  const size_t CH = (size_t)C_DIM * H_DIM;
  const size_t MH = (size_t)M_DIM * H_DIM;
  char* p = (char*)d_ws;
  unsigned short* Wt = (unsigned short*)p; p += L_DIM * CH * sizeof(unsigned short);
  unsigned short* Ha = (unsigned short*)p; p += MH * sizeof(unsigned short);
  unsigned short* Hb = (unsigned short*)p; p += MH * sizeof(unsigned short);
  unsigned short* Z  = (unsigned short*)p; p += MH * sizeof(unsigned short);
  float* psum = (float*)p; p += 128 * H_DIM * sizeof(float);
  float* psqs = (float*)p; p += 128 * H_DIM * sizeof(float);
  float* ss   = (float*)p; p += 2 * H_DIM * sizeof(float);

  f32_to_bf16_kernel<<<2048, 256, 0, stream>>>(x, Ha, (int)(MH / 4));
  wtrans_kernel<<<dim3(H_DIM / 32, C_DIM / 32, L_DIM), dim3(32, 8), 0, stream>>>(W, Wt);

  unsigned short* cur = Ha;
  unsigned short* nxt = Hb;
  for (int l = 0; l < L_DIM; ++l) {
    gemm_kernel<<<(M_DIM / 256) * (H_DIM / 256), 512, 131072, stream>>>(
        cur, Wt + (size_t)l * CH, Z, psum, psqs);
    bn_finalize_kernel<<<4, 256, 0, stream>>>(psum, psqs, gamma + (size_t)l * H_DIM,
                                              beta + (size_t)l * H_DIM, ss);
    bn_recur_kernel<<<BH_DIM / 512, 256, 0, stream>>>(Z, ss, u + (size_t)l * H_DIM, nxt);
    unsigned short* tmp = cur; cur = nxt; nxt = tmp;
  }
  classifier_kernel<<<dim3(4, B_DIM), 256, 0, stream>>>(
      cur + (size_t)(T_DIM - 1) * BH_DIM, Wc, bc, out);
}